// Round 1
// baseline (883.292 us; speedup 1.0000x reference)
//
#include <hip/hip_runtime.h>

// DynamicUpsamplingFilter: per-pixel (3x25)@(25x16) matmul.
// x:      (1, 3, 25, 128, 128)  fp32
// filters:(1, 25, 16, 25, 128, 128) fp32
// out:    (1, 48, 25, 128, 128) fp32, out[(c*16+u)] = sum_k patch[c][k]*filt[k][u]
//
// Memory-bound: filters 65.5MB read-once + out 78.6MB write-once dominate.
// One thread per pixel; k-outer loop (3 cached x loads), u-inner (coalesced
// filter loads along w), 48 fp32 accumulators.

#define T_ 25
#define H_ 128
#define W_ 128
#define C_ 3
#define U_ 16
#define KH_ 5
#define KW_ 5
#define HW_ (H_ * W_)       // 16384
#define THW_ (T_ * HW_)     // 409600

__global__ __launch_bounds__(256) void duf_kernel(
    const float* __restrict__ x,     // (3, 25, 128, 128)
    const float* __restrict__ filt,  // (25, 16, 25, 128, 128)
    float* __restrict__ out)         // (48, 25, 128, 128)
{
    const int p = blockIdx.x * blockDim.x + threadIdx.x;  // [0, THW_) exact grid
    const int t = p / HW_;
    const int rem = p - t * HW_;
    const int h = rem / W_;
    const int w = rem - h * W_;

    float acc[C_][U_];
#pragma unroll
    for (int c = 0; c < C_; ++c)
#pragma unroll
        for (int u = 0; u < U_; ++u) acc[c][u] = 0.f;

    // Base pointer for the x patch center (t, h, w), channel 0.
    const float* xb = x + (size_t)t * HW_ + (size_t)h * W_ + w;

#pragma unroll
    for (int a = 0; a < KH_; ++a) {
        const int hh = h + a - 2;
        const bool hok = (hh >= 0) & (hh < H_);
#pragma unroll
        for (int b = 0; b < KW_; ++b) {
            const int ww = w + b - 2;
            const bool ok = hok & (ww >= 0) & (ww < W_);
            const int k = a * KW_ + b;
            const int off = (a - 2) * W_ + (b - 2);
            float p0 = 0.f, p1 = 0.f, p2 = 0.f;
            if (ok) {
                p0 = xb[0 * T_ * HW_ + off];
                p1 = xb[1 * T_ * HW_ + off];
                p2 = xb[2 * T_ * HW_ + off];
            }
            const float* fp = filt + (size_t)k * U_ * THW_ + p;
#pragma unroll
            for (int u = 0; u < U_; ++u) {
                const float f = fp[(size_t)u * THW_];
                acc[0][u] += p0 * f;
                acc[1][u] += p1 * f;
                acc[2][u] += p2 * f;
            }
        }
    }

#pragma unroll
    for (int c = 0; c < C_; ++c)
#pragma unroll
        for (int u = 0; u < U_; ++u)
            out[(size_t)(c * U_ + u) * THW_ + p] = acc[c][u];
}

extern "C" void kernel_launch(void* const* d_in, const int* in_sizes, int n_in,
                              void* d_out, int out_size, void* d_ws, size_t ws_size,
                              hipStream_t stream) {
    const float* x = (const float*)d_in[0];
    const float* filt = (const float*)d_in[1];
    float* out = (float*)d_out;
    dim3 grid(THW_ / 256);  // 1600 blocks, exact
    dim3 block(256);
    duf_kernel<<<grid, block, 0, stream>>>(x, filt, out);
}